// Round 7
// baseline (126.778 us; speedup 1.0000x reference)
//
#include <hip/hip_runtime.h>
#include <hip/hip_bf16.h>
#include <hip/hip_cooperative_groups.h>

namespace cg = cooperative_groups;

#define SEQ 4096
#define DIM 1024

typedef __attribute__((ext_vector_type(8))) short short8;
typedef __attribute__((ext_vector_type(4))) float f32x4;
typedef __attribute__((ext_vector_type(4))) unsigned short us4;

__device__ __forceinline__ us4 cvt4(float a, float b, float c, float d) {
    union { us4 u; __hip_bfloat162 h[2]; } r;
    r.h[0] = __float22bfloat162_rn(make_float2(a, b));
    r.h[1] = __float22bfloat162_rn(make_float2(c, d));
    return r.u;
}

// One cooperative kernel, 192 blocks x 512 thr.
// Phase 1: blocks 0..63  -> bucket mean (b,p) into wsA (MFMA A-frag layout)
//          blocks 64..191 -> W f32->bf16 into wsB (MFMA B-frag layout)
// grid.sync()
// Phase 2: blocks 0..63  -> 16-col GEMM tile (R5 k_gemm body, proven)
__global__ __launch_bounds__(512) void k_coop(
    const float* __restrict__ latent,   // [8][SEQ][DIM]
    const int*   __restrict__ mask,     // [8][SEQ]
    const float* __restrict__ Wm,       // [DIM][DIM]
    const float* __restrict__ bias,     // [DIM]
    float*       __restrict__ out,      // [64][DIM]
    unsigned short* __restrict__ wsA,   // 64x1024 bf16
    unsigned short* __restrict__ wsB)   // 1024x1024 bf16
{
    __shared__ int    s_pos[8];
    __shared__ float4 s_part[256];      // parity-split partial sums
    __shared__ f32x4  sred[4][64];      // phase-2 kh reduce

    const int blk  = blockIdx.x;
    const int tid  = threadIdx.x;
    const int lane = tid & 63;
    const int wid  = tid >> 6;

    if (blk < 64) {
        // ---- Phase 1a: bucket mean for (b = blk>>3, p = blk&7) ----
        const int b = blk >> 3;
        const int p = blk & 7;

        if (wid == 0) {   // wave 0: early-exit scan for first-8 one positions
            if (lane < 8) s_pos[lane] = SEQ;
            int carry = 0;
            for (int ch = 0; ch < SEQ / 256 && carry < 8; ++ch) {
                const int4 m = *(const int4*)(mask + (size_t)b * SEQ + ch * 256 + lane * 4);
                const int cnt = m.x + m.y + m.z + m.w;
                int v = cnt;
                #pragma unroll
                for (int off = 1; off < 64; off <<= 1) {
                    int o = __shfl_up(v, off, 64);
                    if (lane >= off) v += o;
                }
                const int excl = carry + v - cnt;
                if (excl < 8 && cnt > 0) {
                    int vals[4] = {m.x, m.y, m.z, m.w};
                    int rank = excl;
                    #pragma unroll
                    for (int i = 0; i < 4; ++i) {
                        if (vals[i]) {
                            if (rank < 8) s_pos[rank] = ch * 256 + lane * 4 + i;
                            ++rank;
                        }
                    }
                }
                carry += __shfl(v, 63, 64);
            }
        }
        __syncthreads();

        const int start = (p == 0) ? 0 : s_pos[p - 1] + 1;
        const int endi  = min(s_pos[p], SEQ - 1);
        const int g     = tid >> 8;      // row-parity group 0/1
        const int t256  = tid & 255;     // f4 column 0..255
        const float4* lb = (const float4*)(latent + (size_t)b * SEQ * DIM);
        float4 acc = make_float4(0.f, 0.f, 0.f, 0.f);
        for (int r = start + g; r <= endi; r += 2) {   // coalesced 1KB/instr
            float4 v = lb[(size_t)r * (DIM / 4) + t256];
            acc.x += v.x; acc.y += v.y; acc.z += v.z; acc.w += v.w;
        }
        if (g == 1) s_part[t256] = acc;
        __syncthreads();
        if (g == 0) {
            float4 o = s_part[t256];
            acc.x += o.x; acc.y += o.y; acc.z += o.z; acc.w += o.w;
            const float inv = (endi >= start) ? 1.0f / (float)(endi - start + 1) : 0.0f;
            const int r   = blk;                        // output row b*8+p
            const int rt  = r >> 4, l15 = r & 15;
            const int k0  = t256 * 4;
            const int ks  = k0 >> 5;
            const int lk  = (k0 >> 3) & 3;
            const int j   = k0 & 7;                     // 0 or 4
            *(us4*)&wsA[(size_t)(rt * 32 + ks) * 512 + (lk * 16 + l15) * 8 + j] =
                cvt4(acc.x * inv, acc.y * inv, acc.z * inv, acc.w * inv);
        }
    } else {
        // ---- Phase 1b: W conversion, 128 blocks x 8 cols (wave = col) ----
        const int col = (blk - 64) * 8 + wid;
        const int ct  = col >> 4, l15 = col & 15;
        const float* wr = Wm + (size_t)col * DIM;
        #pragma unroll
        for (int q = 0; q < 4; ++q) {
            const int k = q * 256 + lane * 4;           // coalesced 1KB/instr
            float4 v = *(const float4*)(wr + k);
            const int ks = k >> 5;
            const int lk = (k >> 3) & 3;
            const int j  = k & 7;
            *(us4*)&wsB[(size_t)(ct * 32 + ks) * 512 + (lk * 16 + l15) * 8 + j] =
                cvt4(v.x, v.y, v.z, v.w);
        }
    }

    __threadfence();                 // release: flush L2 (cross-XCD visibility)
    cg::this_grid().sync();
    __threadfence();                 // acquire: invalidate stale L2 lines

    if (blk < 64) {
        // ---- Phase 2: GEMM tile ct = blk (R5 k_gemm body) ----
        const int ct = blk;
        const int rt = wid & 3;
        const int kh = wid >> 2;
        const short8* A = (const short8*)wsA;   // (rt*32+ks)*64 + lane
        const short8* B = (const short8*)wsB;   // (ct*32+ks)*64 + lane

        f32x4 acc = {0.f, 0.f, 0.f, 0.f};
        #pragma unroll
        for (int s = 0; s < 16; ++s) {
            const int ks = kh * 16 + s;
            short8 a  = A[(size_t)(rt * 32 + ks) * 64 + lane];
            short8 bb = B[(size_t)(ct * 32 + ks) * 64 + lane];
            acc = __builtin_amdgcn_mfma_f32_16x16x32_bf16(a, bb, acc, 0, 0, 0);
        }

        if (kh == 1) sred[rt][lane] = acc;
        __syncthreads();
        if (kh == 0) {
            f32x4 o = sred[rt][lane];
            acc = acc + o;                      // fixed order: deterministic
            const int l15 = lane & 15, lk = lane >> 4;
            const int col = ct * 16 + l15;
            const float bv = bias[col];
            #pragma unroll
            for (int j = 0; j < 4; ++j)         // D: row=(lane>>4)*4+j
                out[(size_t)(rt * 16 + lk * 4 + j) * DIM + col] = acc[j] + bv;
        }
    }
}

extern "C" void kernel_launch(void* const* d_in, const int* in_sizes, int n_in,
                              void* d_out, int out_size, void* d_ws, size_t ws_size,
                              hipStream_t stream) {
    const float* latent = (const float*)d_in[0];   // (8,4096,1024) f32
    const int*   mask   = (const int*)d_in[1];     // (8,4096,1) int32
    const float* Wm     = (const float*)d_in[2];   // (1024,1024) f32
    const float* bias   = (const float*)d_in[3];   // (1024,) f32
    float* out = (float*)d_out;                    // (8,8,1024) f32

    unsigned short* wsA = (unsigned short*)d_ws;          // 128 KB
    unsigned short* wsB = wsA + (size_t)64 * DIM;         // 2 MB

    void* args[] = { (void*)&latent, (void*)&mask, (void*)&Wm, (void*)&bias,
                     (void*)&out, (void*)&wsA, (void*)&wsB };
    hipLaunchCooperativeKernel((void*)k_coop, dim3(192), dim3(512),
                               args, 0, stream);
}

// Round 8
// 14.672 us; speedup vs baseline: 8.6409x; 8.6409x over previous
//
#include <hip/hip_runtime.h>
#include <hip/hip_bf16.h>

#define SEQ 4096
#define DIM 1024

typedef __attribute__((ext_vector_type(8))) short short8;
typedef __attribute__((ext_vector_type(4))) float f32x4;
typedef __attribute__((ext_vector_type(4))) unsigned short us4;

__device__ __forceinline__ us4 cvt4(float a, float b, float c, float d) {
    union { us4 u; __hip_bfloat162 h[2]; } r;
    r.h[0] = __float22bfloat162_rn(make_float2(a, b));
    r.h[1] = __float22bfloat162_rn(make_float2(c, d));
    return r.u;
}

// Single plain kernel, 64 blocks x 512 thr (8 waves). Block ct: out cols
// ct*16..+15, all 64 rows. No cross-block communication.
//  W stage : coalesced 64KB slice -> bf16 LDS (swizzled) -> 16 B-frags/wave in VGPR
//  A stage : wave w streams batch w rows 0..pos[7], 4-row lookahead groups,
//            wave-uniform bucket emission -> sA frag layout (XOR-swizzled)
//  C stage : 16 MFMAs/wave (A from LDS, B from VGPR), kh-pair reduce, +bias.
__global__ __launch_bounds__(512) void k_one(
    const float* __restrict__ latent,   // [8][SEQ][DIM]
    const int*   __restrict__ mask,     // [8][SEQ]
    const float* __restrict__ Wm,       // [DIM][DIM] row-major
    const float* __restrict__ bias,     // [DIM]
    float*       __restrict__ out)      // [64][DIM]
{
    __shared__ unsigned short sA[64 * 1024];   // 128 KB; first 32 KB doubles as W stage
    __shared__ int s_pos[8][8];

    const int ct   = blockIdx.x;       // 0..63
    const int tid  = threadIdx.x;
    const int lane = tid & 63;
    const int wid  = tid >> 6;         // 0..7

    // ---- W stage: 16 cols x 1024 k, coalesced f32 load -> bf16 LDS ----
    unsigned short* wlds = sA;         // [16 rows][128 units of 16B], unit-swizzled
    {
        const float4* wbase = (const float4*)(Wm + (size_t)ct * 16 * DIM);
        #pragma unroll
        for (int i = 0; i < 8; ++i) {
            const int f = i * 512 + tid;            // f4 index over 16x256
            float4 v = wbase[f];
            const int c    = f >> 8;                // col-in-slice 0..15
            const int k4   = f & 255;
            const int unit = (k4 >> 1) ^ (c & 7);   // bank-spread swizzle
            *(us4*)&wlds[c * 1024 + unit * 8 + (k4 & 1) * 4] = cvt4(v.x, v.y, v.z, v.w);
        }
    }

    // ---- mask scan: wave w -> batch w, early-exit (wave-local s_pos row) ----
    {
        const int b = wid;
        if (lane < 8) s_pos[wid][lane] = SEQ;       // sentinel
        int carry = 0;
        for (int ch = 0; ch < SEQ / 256 && carry < 8; ++ch) {
            const int4 m = *(const int4*)(mask + (size_t)b * SEQ + ch * 256 + lane * 4);
            const int cnt = m.x + m.y + m.z + m.w;
            int v = cnt;
            #pragma unroll
            for (int off = 1; off < 64; off <<= 1) {
                int o = __shfl_up(v, off, 64);
                if (lane >= off) v += o;
            }
            const int excl = carry + v - cnt;
            if (excl < 8 && cnt > 0) {
                int vals[4] = {m.x, m.y, m.z, m.w};
                int rank = excl;
                #pragma unroll
                for (int i = 0; i < 4; ++i) {
                    if (vals[i]) {
                        if (rank < 8) s_pos[wid][rank] = ch * 256 + lane * 4 + i;
                        ++rank;
                    }
                }
            }
            carry += __shfl(v, 63, 64);
        }
    }
    __syncthreads();                    // W staged in LDS

    // ---- each wave pulls its 16 W-frags into VGPRs ----
    const int rt  = wid & 3;
    const int kh  = wid >> 2;
    const int c15 = lane & 15;
    const int lk  = lane >> 4;          // 0..3
    short8 bfrag[16];
    #pragma unroll
    for (int s = 0; s < 16; ++s) {
        const int ks   = kh * 16 + s;
        const int unit = (ks * 4 + lk) ^ (c15 & 7);
        bfrag[s] = *(const short8*)&wlds[c15 * 1024 + unit * 8];
    }
    __syncthreads();                    // W region free; sA may be overwritten

    // ---- A stage: wave w streams batch w, 4-row lookahead, bucket emission ----
    {
        const int b = wid;
        const float4* lb = (const float4*)(latent + (size_t)b * SEQ * DIM);
        const int lim = min(s_pos[b][7], SEQ - 1);
        int p = 0;
        int np = s_pos[b][0];
        int startr = 0;
        float4 a0 = {0,0,0,0}, a1 = {0,0,0,0}, a2 = {0,0,0,0}, a3 = {0,0,0,0};

        for (int base = 0; base <= lim; base += 4) {
            float4 v[4][4];
            #pragma unroll
            for (int rr = 0; rr < 4; ++rr) {        // issue 16 loads together
                const int r = min(base + rr, SEQ - 1);
                const float4* rp = lb + (size_t)r * (DIM / 4);
                v[rr][0] = rp[lane];       v[rr][1] = rp[64 + lane];
                v[rr][2] = rp[128 + lane]; v[rr][3] = rp[192 + lane];
            }
            #pragma unroll
            for (int rr = 0; rr < 4; ++rr) {
                const int r = base + rr;
                if (r > lim) break;                  // wave-uniform
                a0.x += v[rr][0].x; a0.y += v[rr][0].y; a0.z += v[rr][0].z; a0.w += v[rr][0].w;
                a1.x += v[rr][1].x; a1.y += v[rr][1].y; a1.z += v[rr][1].z; a1.w += v[rr][1].w;
                a2.x += v[rr][2].x; a2.y += v[rr][2].y; a2.z += v[rr][2].z; a2.w += v[rr][2].w;
                a3.x += v[rr][3].x; a3.y += v[rr][3].y; a3.z += v[rr][3].z; a3.w += v[rr][3].w;
                if (r == np) {                       // bucket p ends here
                    const float inv = 1.0f / (float)(r - startr + 1);
                    const int rout = b * 8 + p;
                    const int rtw  = rout >> 4, cw = rout & 15;
                    #pragma unroll
                    for (int q = 0; q < 4; ++q) {
                        const float4 aq = (q == 0) ? a0 : (q == 1) ? a1 : (q == 2) ? a2 : a3;
                        const int ksq = q * 8 + (lane >> 3);
                        const int lkq = (lane >> 1) & 3;
                        const int ing = (lkq * 16 + cw) ^ (ksq & 15);
                        *(us4*)&sA[((rtw * 32 + ksq) * 64 + ing) * 8 + (lane & 1) * 4] =
                            cvt4(aq.x * inv, aq.y * inv, aq.z * inv, aq.w * inv);
                    }
                    a0 = {0,0,0,0}; a1 = {0,0,0,0}; a2 = {0,0,0,0}; a3 = {0,0,0,0};
                    startr = r + 1;
                    ++p;
                    np = (p < 8) ? s_pos[b][p] : -1;
                }
            }
        }
        // trailing sentinel buckets (mask had <8 ones in range)
        while (p < 8) {
            const int count = lim - startr + 1;
            const float inv = (count > 0) ? 1.0f / (float)count : 0.0f;
            const int rout = b * 8 + p;
            const int rtw  = rout >> 4, cw = rout & 15;
            #pragma unroll
            for (int q = 0; q < 4; ++q) {
                const float4 aq = (q == 0) ? a0 : (q == 1) ? a1 : (q == 2) ? a2 : a3;
                const int ksq = q * 8 + (lane >> 3);
                const int lkq = (lane >> 1) & 3;
                const int ing = (lkq * 16 + cw) ^ (ksq & 15);
                *(us4*)&sA[((rtw * 32 + ksq) * 64 + ing) * 8 + (lane & 1) * 4] =
                    cvt4(aq.x * inv, aq.y * inv, aq.z * inv, aq.w * inv);
            }
            a0 = {0,0,0,0}; a1 = {0,0,0,0}; a2 = {0,0,0,0}; a3 = {0,0,0,0};
            startr = lim + 1;
            ++p;
        }
    }
    __syncthreads();                    // sA complete

    // ---- C stage: MFMA (A from LDS swizzled, B from VGPR) ----
    f32x4 acc = {0.f, 0.f, 0.f, 0.f};
    #pragma unroll
    for (int s = 0; s < 16; ++s) {
        const int ks  = kh * 16 + s;
        const int ing = lane ^ (ks & 15);
        short8 a = *(const short8*)&sA[((rt * 32 + ks) * 64 + ing) * 8];
        acc = __builtin_amdgcn_mfma_f32_16x16x32_bf16(a, bfrag[s], acc, 0, 0, 0);
    }

    __syncthreads();                    // all sA reads done; safe to alias
    f32x4* sred = (f32x4*)sA;           // 4 KB alias
    if (kh == 1) sred[rt * 64 + lane] = acc;
    __syncthreads();
    if (kh == 0) {
        f32x4 o = sred[rt * 64 + lane];
        acc = acc + o;                   // fixed order: deterministic
        const int col = ct * 16 + c15;
        const float bv = bias[col];
        #pragma unroll
        for (int j = 0; j < 4; ++j)      // D: row = rt*16 + lk*4 + j
            out[(size_t)(rt * 16 + lk * 4 + j) * DIM + col] = acc[j] + bv;
    }
}

extern "C" void kernel_launch(void* const* d_in, const int* in_sizes, int n_in,
                              void* d_out, int out_size, void* d_ws, size_t ws_size,
                              hipStream_t stream) {
    const float* latent = (const float*)d_in[0];   // (8,4096,1024) f32
    const int*   mask   = (const int*)d_in[1];     // (8,4096,1) int32
    const float* Wm     = (const float*)d_in[2];   // (1024,1024) f32
    const float* bias   = (const float*)d_in[3];   // (1024,) f32
    float* out = (float*)d_out;                    // (8,8,1024) f32

    k_one<<<64, 512, 0, stream>>>(latent, mask, Wm, bias, out);
}

// Round 9
// 14.660 us; speedup vs baseline: 8.6477x; 1.0008x over previous
//
#include <hip/hip_runtime.h>
#include <hip/hip_bf16.h>

#define SEQ 4096
#define DIM 1024

typedef __attribute__((ext_vector_type(8))) short short8;
typedef __attribute__((ext_vector_type(4))) float f32x4;
typedef __attribute__((ext_vector_type(4))) unsigned short us4;

__device__ __forceinline__ us4 cvt4(float a, float b, float c, float d) {
    union { us4 u; __hip_bfloat162 h[2]; } r;
    r.h[0] = __float22bfloat162_rn(make_float2(a, b));
    r.h[1] = __float22bfloat162_rn(make_float2(c, d));
    return r.u;
}

// Single kernel, 64 blocks x 512 thr (8 waves). Block ct: out cols ct*16..+15.
// Latency plan: mask chunk + rows 0..7 (always needed: lim>=7) + W slice are
// all issued before the first wait, so one HBM round trip covers all three.
__global__ __launch_bounds__(512) void k_one(
    const float* __restrict__ latent,   // [8][SEQ][DIM]
    const int*   __restrict__ mask,     // [8][SEQ]
    const float* __restrict__ Wm,       // [DIM][DIM] row-major
    const float* __restrict__ bias,     // [DIM]
    float*       __restrict__ out)      // [64][DIM]
{
    __shared__ unsigned short sA[64 * 1024];   // 128 KB; first 32 KB = W stage
    __shared__ f32x4 sred[4][64];              // separate: saves a barrier
    __shared__ int s_pos[8][8];

    const int ct   = blockIdx.x;
    const int tid  = threadIdx.x;
    const int lane = tid & 63;
    const int wid  = tid >> 6;         // 0..7 = batch
    const int b    = wid;

    // ---- issue everything independent up front ----
    const int4 m0 = *(const int4*)(mask + (size_t)b * SEQ + lane * 4);

    const float4* lb = (const float4*)(latent + (size_t)b * SEQ * DIM);
    float4 pv[8][4];                   // speculative rows 0..7 (always needed)
    #pragma unroll
    for (int rr = 0; rr < 8; ++rr) {
        const float4* rp = lb + (size_t)rr * (DIM / 4);
        pv[rr][0] = rp[lane];       pv[rr][1] = rp[64 + lane];
        pv[rr][2] = rp[128 + lane]; pv[rr][3] = rp[192 + lane];
    }

    const float4* wbase = (const float4*)(Wm + (size_t)ct * 16 * DIM);
    float4 wv[8];
    #pragma unroll
    for (int i = 0; i < 8; ++i) wv[i] = wbase[i * 512 + tid];

    // ---- mask scan (chunk 0 preloaded; extra chunks only if <8 ones found) ----
    if (lane < 8) s_pos[wid][lane] = SEQ;     // sentinel
    {
        int carry = 0;
        int4 m = m0;
        for (int ch = 0; ch < SEQ / 256 && carry < 8; ++ch) {
            if (ch) m = *(const int4*)(mask + (size_t)b * SEQ + ch * 256 + lane * 4);
            const int cnt = m.x + m.y + m.z + m.w;
            int v = cnt;
            #pragma unroll
            for (int off = 1; off < 64; off <<= 1) {
                int o = __shfl_up(v, off, 64);
                if (lane >= off) v += o;
            }
            const int excl = carry + v - cnt;
            if (excl < 8 && cnt > 0) {
                int vals[4] = {m.x, m.y, m.z, m.w};
                int rank = excl;
                #pragma unroll
                for (int i = 0; i < 4; ++i) {
                    if (vals[i]) {
                        if (rank < 8) s_pos[wid][rank] = ch * 256 + lane * 4 + i;
                        ++rank;
                    }
                }
            }
            carry += __shfl(v, 63, 64);
        }
    }

    // ---- W cvt -> LDS (swizzled 16B units) ----
    unsigned short* wlds = sA;
    #pragma unroll
    for (int i = 0; i < 8; ++i) {
        const int f    = i * 512 + tid;
        const int c    = f >> 8;
        const int k4   = f & 255;
        const int unit = (k4 >> 1) ^ (c & 7);
        *(us4*)&wlds[c * 1024 + unit * 8 + (k4 & 1) * 4] =
            cvt4(wv[i].x, wv[i].y, wv[i].z, wv[i].w);
    }
    __syncthreads();                   // bar1: W in LDS, s_pos ready

    // ---- bfrag pull ----
    const int rt  = wid & 3;
    const int kh  = wid >> 2;
    const int c15 = lane & 15;
    const int lk  = lane >> 4;
    short8 bfrag[16];
    #pragma unroll
    for (int s = 0; s < 16; ++s) {
        const int ks   = kh * 16 + s;
        const int unit = (ks * 4 + lk) ^ (c15 & 7);
        bfrag[s] = *(const short8*)&wlds[c15 * 1024 + unit * 8];
    }
    __syncthreads();                   // bar2: W region free

    // ---- A stage: consume prefetched rows 0..7, then stream with lookahead 8 ----
    {
        const int lim = min(s_pos[b][7], SEQ - 1);
        int p = 0, startr = 0;
        int np = s_pos[b][0];
        float4 A0 = {0,0,0,0}, A1 = {0,0,0,0}, A2 = {0,0,0,0}, A3 = {0,0,0,0};

        #define EMIT(INV)                                                        \
        {                                                                        \
            const float inv_ = (INV);                                            \
            const int rout = b * 8 + p;                                          \
            const int rtw = rout >> 4, cw = rout & 15;                           \
            const float4 aq0 = A0, aq1 = A1, aq2 = A2, aq3 = A3;                 \
            _Pragma("unroll")                                                    \
            for (int q = 0; q < 4; ++q) {                                        \
                const float4 aq = (q==0)?aq0:(q==1)?aq1:(q==2)?aq2:aq3;          \
                const int ksq = q * 8 + (lane >> 3);                             \
                const int lkq = (lane >> 1) & 3;                                 \
                const int ing = (lkq * 16 + cw) ^ (ksq & 15);                    \
                *(us4*)&sA[((rtw * 32 + ksq) * 64 + ing) * 8 + (lane & 1) * 4] = \
                    cvt4(aq.x * inv_, aq.y * inv_, aq.z * inv_, aq.w * inv_);    \
            }                                                                    \
            A0 = {0,0,0,0}; A1 = {0,0,0,0}; A2 = {0,0,0,0}; A3 = {0,0,0,0};      \
        }

        #pragma unroll
        for (int rr = 0; rr < 8; ++rr) {           // rows 0..7 (prefetched)
            A0.x += pv[rr][0].x; A0.y += pv[rr][0].y; A0.z += pv[rr][0].z; A0.w += pv[rr][0].w;
            A1.x += pv[rr][1].x; A1.y += pv[rr][1].y; A1.z += pv[rr][1].z; A1.w += pv[rr][1].w;
            A2.x += pv[rr][2].x; A2.y += pv[rr][2].y; A2.z += pv[rr][2].z; A2.w += pv[rr][2].w;
            A3.x += pv[rr][3].x; A3.y += pv[rr][3].y; A3.z += pv[rr][3].z; A3.w += pv[rr][3].w;
            if (rr == np) {
                EMIT(1.0f / (float)(rr - startr + 1));
                startr = rr + 1; ++p;
                np = (p < 8) ? s_pos[b][p] : -1;
            }
        }

        for (int base = 8; base <= lim; base += 8) {
            float4 v[8][4];
            #pragma unroll
            for (int rr = 0; rr < 8; ++rr) {       // 32 loads in flight
                const int r = min(base + rr, SEQ - 1);
                const float4* rp = lb + (size_t)r * (DIM / 4);
                v[rr][0] = rp[lane];       v[rr][1] = rp[64 + lane];
                v[rr][2] = rp[128 + lane]; v[rr][3] = rp[192 + lane];
            }
            #pragma unroll
            for (int rr = 0; rr < 8; ++rr) {
                const int r = base + rr;
                if (r > lim) break;                 // wave-uniform
                A0.x += v[rr][0].x; A0.y += v[rr][0].y; A0.z += v[rr][0].z; A0.w += v[rr][0].w;
                A1.x += v[rr][1].x; A1.y += v[rr][1].y; A1.z += v[rr][1].z; A1.w += v[rr][1].w;
                A2.x += v[rr][2].x; A2.y += v[rr][2].y; A2.z += v[rr][2].z; A2.w += v[rr][2].w;
                A3.x += v[rr][3].x; A3.y += v[rr][3].y; A3.z += v[rr][3].z; A3.w += v[rr][3].w;
                if (r == np) {
                    EMIT(1.0f / (float)(r - startr + 1));
                    startr = r + 1; ++p;
                    np = (p < 8) ? s_pos[b][p] : -1;
                }
            }
        }
        while (p < 8) {                             // sentinel buckets
            const int count = lim - startr + 1;
            EMIT((count > 0) ? 1.0f / (float)count : 0.0f);
            startr = lim + 1; ++p;
        }
        #undef EMIT
    }
    __syncthreads();                   // bar3: sA complete

    // ---- MFMA (A from LDS swizzled, B from VGPR) ----
    f32x4 acc = {0.f, 0.f, 0.f, 0.f};
    #pragma unroll
    for (int s = 0; s < 16; ++s) {
        const int ks  = kh * 16 + s;
        const int ing = lane ^ (ks & 15);
        short8 a = *(const short8*)&sA[((rt * 32 + ks) * 64 + ing) * 8];
        acc = __builtin_amdgcn_mfma_f32_16x16x32_bf16(a, bfrag[s], acc, 0, 0, 0);
    }

    if (kh == 1) sred[rt][lane] = acc;
    __syncthreads();                   // bar4
    if (kh == 0) {
        f32x4 o = sred[rt][lane];
        acc = acc + o;                 // fixed order: deterministic
        const int col = ct * 16 + c15;
        const float bv = bias[col];
        #pragma unroll
        for (int j = 0; j < 4; ++j)    // D: row = rt*16 + lk*4 + j
            out[(size_t)(rt * 16 + lk * 4 + j) * DIM + col] = acc[j] + bv;
    }
}

extern "C" void kernel_launch(void* const* d_in, const int* in_sizes, int n_in,
                              void* d_out, int out_size, void* d_ws, size_t ws_size,
                              hipStream_t stream) {
    const float* latent = (const float*)d_in[0];   // (8,4096,1024) f32
    const int*   mask   = (const int*)d_in[1];     // (8,4096,1) int32
    const float* Wm     = (const float*)d_in[2];   // (1024,1024) f32
    const float* bias   = (const float*)d_in[3];   // (1024,) f32
    float* out = (float*)d_out;                    // (8,8,1024) f32

    k_one<<<64, 512, 0, stream>>>(latent, mask, Wm, bias, out);
}

// Round 10
// 10.537 us; speedup vs baseline: 12.0319x; 1.3913x over previous
//
#include <hip/hip_runtime.h>
#include <hip/hip_bf16.h>

#define SEQ 4096
#define DIM 1024

typedef __attribute__((ext_vector_type(8))) short short8;
typedef __attribute__((ext_vector_type(4))) float f32x4;
typedef __attribute__((ext_vector_type(4))) unsigned short us4;

__device__ __forceinline__ us4 cvt4(float a, float b, float c, float d) {
    union { us4 u; __hip_bfloat162 h[2]; } r;
    r.h[0] = __float22bfloat162_rn(make_float2(a, b));
    r.h[1] = __float22bfloat162_rn(make_float2(c, d));
    return r.u;
}

// Grid = 256 blocks: (batch b = blk>>5, col-tile ct = blk&31, 32 cols each).
// Block: means for batch b's 8 buckets (wave p owns bucket p; per-wave
// redundant mask scan -> no barrier) + 16x32 MFMA GEMM tile (rows 8-15 zero).
// Per-CU traffic ~300 KB; all 256 CUs active; 2 barriers; no cross-block deps.
__global__ __launch_bounds__(512) void k_one(
    const float* __restrict__ latent,   // [8][SEQ][DIM]
    const int*   __restrict__ mask,     // [8][SEQ]
    const float* __restrict__ Wm,       // [DIM][DIM] row-major
    const float* __restrict__ bias,     // [DIM]
    float*       __restrict__ out)      // [64][DIM]
{
    __shared__ unsigned short sB[32 * 1024];   // 64 KB: B-frags (2 col-groups)
    __shared__ unsigned short sA[16 * 1024];   // 32 KB: A-frags, rows 8-15 = 0
    __shared__ f32x4 sred[2][4][64];           // 8 KB: kh reduce
    __shared__ int s_pos[8][8];                // per-wave scan result

    const int blk  = blockIdx.x;
    const int b    = blk >> 5;         // batch
    const int ct   = blk & 31;         // col tile (32 cols)
    const int tid  = threadIdx.x;
    const int lane = tid & 63;
    const int wid  = tid >> 6;         // 0..7 = bucket p (phase A/B), GEMM wave

    // ---- issue W slice loads up front (32 cols x 1024 k, f32, coalesced) ----
    const float4* wbase = (const float4*)(Wm + (size_t)(ct * 32) * DIM);
    float4 wv[16];
    #pragma unroll
    for (int i = 0; i < 16; ++i) wv[i] = wbase[i * 512 + tid];

    // ---- per-wave redundant mask scan for batch b (own s_pos row) ----
    {
        if (lane < 8) s_pos[wid][lane] = SEQ;       // sentinel
        int carry = 0;
        for (int ch = 0; ch < SEQ / 256 && carry < 8; ++ch) {
            const int4 m = *(const int4*)(mask + (size_t)b * SEQ + ch * 256 + lane * 4);
            const int cnt = m.x + m.y + m.z + m.w;
            int v = cnt;
            #pragma unroll
            for (int off = 1; off < 64; off <<= 1) {
                int o = __shfl_up(v, off, 64);
                if (lane >= off) v += o;
            }
            const int excl = carry + v - cnt;
            if (excl < 8 && cnt > 0) {
                int vals[4] = {m.x, m.y, m.z, m.w};
                int rank = excl;
                #pragma unroll
                for (int i = 0; i < 4; ++i) {
                    if (vals[i]) {
                        if (rank < 8) s_pos[wid][rank] = ch * 256 + lane * 4 + i;
                        ++rank;
                    }
                }
            }
            carry += __shfl(v, 63, 64);
        }
    }

    // ---- W cvt -> sB (B-frag layout, XOR-swizzled 16B units) ----
    #pragma unroll
    for (int i = 0; i < 16; ++i) {
        const int f  = i * 512 + tid;               // f4 idx over 32x256
        const int c  = f >> 8;                      // col-in-slice 0..31
        const int k4 = f & 255;
        const int ks = k4 >> 3;
        const int lk = (k4 >> 1) & 3;
        const int j  = (k4 & 1) * 4;
        const int cg = c >> 4, l15 = c & 15;
        const int su = (lk * 16 + l15) ^ (ks & 7);
        *(us4*)&sB[cg * 16384 + ks * 512 + su * 8 + j] =
            cvt4(wv[i].x, wv[i].y, wv[i].z, wv[i].w);
    }

    // ---- zero sA rows 8..15 (disjoint from bucket writes) ----
    for (int z = tid; z < 1024; z += 512) {
        const int ks  = z >> 5, idx = z & 31;
        const int su  = (idx & 7) + 8 + (idx >> 3) * 16;
        *(short8*)&sA[ks * 512 + su * 8] = (short8){0,0,0,0,0,0,0,0};
    }

    // ---- wave p: bucket p of batch b -> sA row p (A-frag layout) ----
    {
        const int p = wid;
        const int start = (p == 0) ? 0 : s_pos[wid][p - 1] + 1;
        const int endi  = min(s_pos[wid][p], SEQ - 1);
        const float4* lb = (const float4*)(latent + (size_t)b * SEQ * DIM);
        float4 A0 = {0,0,0,0}, A1 = {0,0,0,0}, A2 = {0,0,0,0}, A3 = {0,0,0,0};
        for (int r0 = start; r0 <= endi; r0 += 4) {
            float4 v[4][4];
            #pragma unroll
            for (int rr = 0; rr < 4; ++rr) {        // 16 loads in flight
                const int r = min(r0 + rr, endi);
                const float4* rp = lb + (size_t)r * (DIM / 4);
                v[rr][0] = rp[lane];       v[rr][1] = rp[64 + lane];
                v[rr][2] = rp[128 + lane]; v[rr][3] = rp[192 + lane];
            }
            #pragma unroll
            for (int rr = 0; rr < 4; ++rr) {
                if (r0 + rr > endi) break;          // wave-uniform
                A0.x += v[rr][0].x; A0.y += v[rr][0].y; A0.z += v[rr][0].z; A0.w += v[rr][0].w;
                A1.x += v[rr][1].x; A1.y += v[rr][1].y; A1.z += v[rr][1].z; A1.w += v[rr][1].w;
                A2.x += v[rr][2].x; A2.y += v[rr][2].y; A2.z += v[rr][2].z; A2.w += v[rr][2].w;
                A3.x += v[rr][3].x; A3.y += v[rr][3].y; A3.z += v[rr][3].z; A3.w += v[rr][3].w;
            }
        }
        const float inv = (endi >= start) ? 1.0f / (float)(endi - start + 1) : 0.0f;
        #pragma unroll
        for (int q = 0; q < 4; ++q) {
            const float4 aq = (q == 0) ? A0 : (q == 1) ? A1 : (q == 2) ? A2 : A3;
            const int t  = q * 64 + lane;           // f4 idx 0..255 of row p
            const int ks = t >> 3;
            const int lk = (t >> 1) & 3;
            const int j  = (t & 1) * 4;
            const int su = (lk * 16 + p) ^ (ks & 7);
            *(us4*)&sA[ks * 512 + su * 8 + j] =
                cvt4(aq.x * inv, aq.y * inv, aq.z * inv, aq.w * inv);
        }
    }
    __syncthreads();                   // bar1: sA + sB complete

    // ---- MFMA: wave (cg = wid&1, kh = wid>>1), 8 MFMAs each ----
    const int cg = wid & 1;
    const int kh = wid >> 1;
    f32x4 acc = {0.f, 0.f, 0.f, 0.f};
    #pragma unroll
    for (int s = 0; s < 8; ++s) {
        const int ks = kh * 8 + s;
        const int sl = (lane ^ (ks & 7)) * 8;
        short8 a  = *(const short8*)&sA[ks * 512 + sl];
        short8 bb = *(const short8*)&sB[cg * 16384 + ks * 512 + sl];
        acc = __builtin_amdgcn_mfma_f32_16x16x32_bf16(a, bb, acc, 0, 0, 0);
    }

    if (kh != 0) sred[cg][kh][lane] = acc;
    __syncthreads();                   // bar2
    if (kh == 0) {
        f32x4 r1 = sred[cg][1][lane];
        f32x4 r2 = sred[cg][2][lane];
        f32x4 r3 = sred[cg][3][lane];
        acc = ((acc + r1) + r2) + r3;  // fixed order: deterministic
        if (lane < 32) {               // D rows 0..7 live in lanes 0..31
            const int l15 = lane & 15;
            const int lk2 = lane >> 4; // 0..1
            const int col = ct * 32 + cg * 16 + l15;
            const float bv = bias[col];
            #pragma unroll
            for (int j = 0; j < 4; ++j)    // row = b*8 + lk2*4 + j
                out[(size_t)(b * 8 + lk2 * 4 + j) * DIM + col] = acc[j] + bv;
        }
    }
}

extern "C" void kernel_launch(void* const* d_in, const int* in_sizes, int n_in,
                              void* d_out, int out_size, void* d_ws, size_t ws_size,
                              hipStream_t stream) {
    const float* latent = (const float*)d_in[0];   // (8,4096,1024) f32
    const int*   mask   = (const int*)d_in[1];     // (8,4096,1) int32
    const float* Wm     = (const float*)d_in[2];   // (1024,1024) f32
    const float* bias   = (const float*)d_in[3];   // (1024,) f32
    float* out = (float*)d_out;                    // (8,8,1024) f32

    k_one<<<256, 512, 0, stream>>>(latent, mask, Wm, bias, out);
}

// Round 11
// 10.499 us; speedup vs baseline: 12.0757x; 1.0036x over previous
//
#include <hip/hip_runtime.h>
#include <hip/hip_bf16.h>

#define SEQ 4096
#define DIM 1024

typedef __attribute__((ext_vector_type(8))) short short8;
typedef __attribute__((ext_vector_type(4))) float f32x4;
typedef __attribute__((ext_vector_type(4))) unsigned short us4;

__device__ __forceinline__ us4 cvt4(float a, float b, float c, float d) {
    union { us4 u; __hip_bfloat162 h[2]; } r;
    r.h[0] = __float22bfloat162_rn(make_float2(a, b));
    r.h[1] = __float22bfloat162_rn(make_float2(c, d));
    return r.u;
}

// Grid = 256 blocks: ct = blk&63 (16-col tile), bp = blk>>6 (batch pair).
// Block: full 16x16 output tile = (2 batches x 8 buckets) x 16 cols.
// Wave w: bucket w for both batches (A stage); K-slice w of the GEMM (4 MFMAs).
// W slice 64 KB, 4x L2 replication (same-XCD by blk mapping). 2 barriers.
__global__ __launch_bounds__(512) void k_one(
    const float* __restrict__ latent,   // [8][SEQ][DIM]
    const int*   __restrict__ mask,     // [8][SEQ]
    const float* __restrict__ Wm,       // [DIM][DIM] row-major
    const float* __restrict__ bias,     // [DIM]
    float*       __restrict__ out)      // [64][DIM]
{
    __shared__ unsigned short sB[16 * 1024];   // 32 KB: B-frags (16 cols)
    __shared__ unsigned short sA[16 * 1024];   // 32 KB: A-frags (16 rows)
    __shared__ f32x4 sred[8][64];              // 8 KB: K-slice reduce
    __shared__ int s_pos[8][2][8];             // per-wave, per-batch scan

    const int blk  = blockIdx.x;
    const int ct   = blk & 63;         // col tile (16 cols); low bits -> XCD share
    const int bp   = blk >> 6;         // batch pair 0..3
    const int tid  = threadIdx.x;
    const int lane = tid & 63;
    const int wid  = tid >> 6;         // 0..7

    // ---- issue W slice loads up front (16 cols x 1024 k, coalesced f32) ----
    const float4* wbase = (const float4*)(Wm + (size_t)(ct * 16) * DIM);
    float4 wv[8];
    #pragma unroll
    for (int i = 0; i < 8; ++i) wv[i] = wbase[i * 512 + tid];

    // ---- per-wave redundant mask scan, both batches of the pair ----
    #pragma unroll
    for (int bb = 0; bb < 2; ++bb) {
        const int b = bp * 2 + bb;
        if (lane < 8) s_pos[wid][bb][lane] = SEQ;   // sentinel
        int carry = 0;
        for (int ch = 0; ch < SEQ / 256 && carry < 8; ++ch) {
            const int4 m = *(const int4*)(mask + (size_t)b * SEQ + ch * 256 + lane * 4);
            const int cnt = m.x + m.y + m.z + m.w;
            int v = cnt;
            #pragma unroll
            for (int off = 1; off < 64; off <<= 1) {
                int o = __shfl_up(v, off, 64);
                if (lane >= off) v += o;
            }
            const int excl = carry + v - cnt;
            if (excl < 8 && cnt > 0) {
                int vals[4] = {m.x, m.y, m.z, m.w};
                int rank = excl;
                #pragma unroll
                for (int i = 0; i < 4; ++i) {
                    if (vals[i]) {
                        if (rank < 8) s_pos[wid][bb][rank] = ch * 256 + lane * 4 + i;
                        ++rank;
                    }
                }
            }
            carry += __shfl(v, 63, 64);
        }
    }

    // ---- W cvt -> sB (B-frag layout, XOR-swizzled 16B units) ----
    #pragma unroll
    for (int i = 0; i < 8; ++i) {
        const int f  = i * 512 + tid;               // f4 idx over 16x256
        const int c  = f >> 8;                      // col-in-slice 0..15
        const int k4 = f & 255;
        const int ks = k4 >> 3;
        const int lk = (k4 >> 1) & 3;
        const int j  = (k4 & 1) * 4;
        const int su = (lk * 16 + c) ^ (ks & 7);
        *(us4*)&sB[ks * 512 + su * 8 + j] =
            cvt4(wv[i].x, wv[i].y, wv[i].z, wv[i].w);
    }

    // ---- A stage: wave w -> bucket w of both batches -> sA (A-frag layout) ----
    #pragma unroll
    for (int bb = 0; bb < 2; ++bb) {
        const int b = bp * 2 + bb;
        const int p = wid;
        const int start = (p == 0) ? 0 : s_pos[wid][bb][p - 1] + 1;
        const int endi  = min(s_pos[wid][bb][p], SEQ - 1);
        const float4* lb = (const float4*)(latent + (size_t)b * SEQ * DIM);
        float4 A0 = {0,0,0,0}, A1 = {0,0,0,0}, A2 = {0,0,0,0}, A3 = {0,0,0,0};
        for (int r0 = start; r0 <= endi; r0 += 4) {
            float4 v[4][4];
            #pragma unroll
            for (int rr = 0; rr < 4; ++rr) {        // 16 loads in flight
                const int r = min(r0 + rr, endi);
                const float4* rp = lb + (size_t)r * (DIM / 4);
                v[rr][0] = rp[lane];       v[rr][1] = rp[64 + lane];
                v[rr][2] = rp[128 + lane]; v[rr][3] = rp[192 + lane];
            }
            #pragma unroll
            for (int rr = 0; rr < 4; ++rr) {
                if (r0 + rr > endi) break;          // wave-uniform
                A0.x += v[rr][0].x; A0.y += v[rr][0].y; A0.z += v[rr][0].z; A0.w += v[rr][0].w;
                A1.x += v[rr][1].x; A1.y += v[rr][1].y; A1.z += v[rr][1].z; A1.w += v[rr][1].w;
                A2.x += v[rr][2].x; A2.y += v[rr][2].y; A2.z += v[rr][2].z; A2.w += v[rr][2].w;
                A3.x += v[rr][3].x; A3.y += v[rr][3].y; A3.z += v[rr][3].z; A3.w += v[rr][3].w;
            }
        }
        const float inv = (endi >= start) ? 1.0f / (float)(endi - start + 1) : 0.0f;
        const int rloc = bb * 8 + p;                // local A row 0..15
        #pragma unroll
        for (int q = 0; q < 4; ++q) {
            const float4 aq = (q == 0) ? A0 : (q == 1) ? A1 : (q == 2) ? A2 : A3;
            const int t  = q * 64 + lane;           // f4 idx 0..255 of the row
            const int ks = t >> 3;
            const int lk = (t >> 1) & 3;
            const int j  = (t & 1) * 4;
            const int su = (lk * 16 + rloc) ^ (ks & 7);
            *(us4*)&sA[ks * 512 + su * 8 + j] =
                cvt4(aq.x * inv, aq.y * inv, aq.z * inv, aq.w * inv);
        }
    }
    __syncthreads();                   // bar1: sA + sB complete

    // ---- MFMA: wave w = K-slice w (ks = w*4 .. w*4+3) ----
    f32x4 acc = {0.f, 0.f, 0.f, 0.f};
    #pragma unroll
    for (int s = 0; s < 4; ++s) {
        const int ks = wid * 4 + s;
        const int sl = (lane ^ (ks & 7)) * 8;
        short8 a  = *(const short8*)&sA[ks * 512 + sl];
        short8 bb = *(const short8*)&sB[ks * 512 + sl];
        acc = __builtin_amdgcn_mfma_f32_16x16x32_bf16(a, bb, acc, 0, 0, 0);
    }

    if (wid != 0) sred[wid][lane] = acc;
    __syncthreads();                   // bar2
    if (wid == 0) {
        #pragma unroll
        for (int r = 1; r < 8; ++r) {  // fixed order: deterministic
            f32x4 o = sred[r][lane];
            acc = acc + o;
        }
        const int l15 = lane & 15;
        const int lk  = lane >> 4;     // 0..3
        const int col = ct * 16 + l15;
        const float bv = bias[col];
        #pragma unroll
        for (int j = 0; j < 4; ++j) {  // D: local row = lk*4 + j (0..15)
            const int rloc = lk * 4 + j;
            const int b    = bp * 2 + (rloc >> 3);
            const int p    = rloc & 7;
            out[(size_t)(b * 8 + p) * DIM + col] = acc[j] + bv;
        }
    }
}

extern "C" void kernel_launch(void* const* d_in, const int* in_sizes, int n_in,
                              void* d_out, int out_size, void* d_ws, size_t ws_size,
                              hipStream_t stream) {
    const float* latent = (const float*)d_in[0];   // (8,4096,1024) f32
    const int*   mask   = (const int*)d_in[1];     // (8,4096,1) int32
    const float* Wm     = (const float*)d_in[2];   // (1024,1024) f32
    const float* bias   = (const float*)d_in[3];   // (1024,) f32
    float* out = (float*)d_out;                    // (8,8,1024) f32

    k_one<<<256, 512, 0, stream>>>(latent, mask, Wm, bias, out);
}